// Round 8
// baseline (223.892 us; speedup 1.0000x reference)
//
#include <hip/hip_runtime.h>

typedef __bf16 bf16x8 __attribute__((ext_vector_type(8)));
typedef float floatx4 __attribute__((ext_vector_type(4)));

#define XS 136  // LDS row stride in bf16 elements (272 B -> 2-way bank aliasing = free)

__device__ __forceinline__ unsigned short f32_bf16(float f) {
    union { float f; unsigned int u; } c; c.f = f;
    return (unsigned short)((c.u + 0x7fffu + ((c.u >> 16) & 1u)) >> 16);  // RNE, finite inputs
}

// w1 -> MFMA B-fragment order, hidden-col mapping h(nt,l15) = l15*32 + nt.
// frag f = (e*32+nt)*4+ks ; lane (quad,l15) holds B[k=quad*8+j][n=l15] = w1[e][h][k]
__global__ __launch_bounds__(256) void prep_w1_frag(const float* __restrict__ w1,
                                                    unsigned short* __restrict__ wbf) {
    int g    = blockIdx.x * 256 + threadIdx.x;   // 64 blocks -> 16384 threads
    int lane = g & 63;
    int frag = g >> 6;                            // 0..255
    int ks   = frag & 3;
    int nt   = (frag >> 2) & 31;
    int e    = frag >> 7;
    int l15  = lane & 15;
    int quad = lane >> 4;
    int h    = l15 * 32 + nt;
    const float* src = w1 + ((e * 512 + h) * 128 + ks * 32 + quad * 8);
    unsigned short* dst = wbf + (long)g * 8;      // 16 B/lane, contiguous per wave
    #pragma unroll
    for (int j = 0; j < 8; ++j) dst[j] = f32_bf16(src[j]);
}

__device__ __forceinline__ void red_store(float v0, float v1, int r, int e,
                                          float (*outs)[2][2], int l15) {
    v0 += __shfl_xor(v0, 1);  v1 += __shfl_xor(v1, 1);
    v0 += __shfl_xor(v0, 2);  v1 += __shfl_xor(v1, 2);
    v0 += __shfl_xor(v0, 4);  v1 += __shfl_xor(v1, 4);
    v0 += __shfl_xor(v0, 8);  v1 += __shfl_xor(v1, 8);
    if (l15 == 0) { outs[r][e][0] = v0; outs[r][e][1] = v1; }
}

// Low-register-pressure shape: wave owns 32 rows (2 m-tiles, A = 8 named bf16x8
// = 32 VGPRs, LDS-read ONCE) and loops over BOTH experts x 32 nt. All 4 waves
// of a block read the same weight stream (L1-shared). outp regs reused across
// the expert loop. Peak unified regs ~90 < 128 cap at (256,4) -> no spill.
__global__ __launch_bounds__(256, 4) void moe_fused(
    const float* __restrict__ x,
    const unsigned short* __restrict__ wbf,   // fragment-ordered bf16 w1
    const float* __restrict__ b1,             // [2][512]
    const float* __restrict__ w2,             // [2][2][512]
    const float* __restrict__ b2,             // [2][2]
    const float* __restrict__ protos,         // [2][128]
    float* __restrict__ out)                  // [B][2]
{
    __shared__ unsigned short xs[128 * XS];   // 34816 B
    __shared__ float out_s[128][2][2];        // 2048 B
    __shared__ int   t_s[128];                // 512 B -> 37376 B => 4 blocks/CU

    const int tid  = threadIdx.x;
    const int lane = tid & 63;
    const int wave = tid >> 6;
    const int quad = lane >> 4;
    const int l15  = lane & 15;
    const long rowbase = (long)blockIdx.x * 128;

    // ---- routing: t = (d1<d0) via sign of sum (p0-p1)*(0.5*(p0+p1)-x), fp64 ----
    {
        int r   = tid >> 1;                   // 2 threads per row
        int sub = tid & 1;
        const float* xr = x + (rowbase + r) * 128 + sub * 64;
        const float* p0 = protos + sub * 64;
        const float* p1 = protos + 128 + sub * 64;
        double acc = 0.0;
        #pragma unroll
        for (int k = 0; k < 16; ++k) {
            float4 xv = *(const float4*)(xr + k * 4);
            float4 a  = *(const float4*)(p0 + k * 4);
            float4 b  = *(const float4*)(p1 + k * 4);
            acc += ((double)a.x - b.x) * (0.5 * ((double)a.x + b.x) - xv.x);
            acc += ((double)a.y - b.y) * (0.5 * ((double)a.y + b.y) - xv.y);
            acc += ((double)a.z - b.z) * (0.5 * ((double)a.z + b.z) - xv.z);
            acc += ((double)a.w - b.w) * (0.5 * ((double)a.w + b.w) - xv.w);
        }
        acc += __shfl_xor(acc, 1);
        if (sub == 0) t_s[r] = (acc > 0.0) ? 1 : 0;   // tie -> expert 0 (numpy argmin)
    }

    // ---- stage x tile: coalesced float4 global reads -> bf16 LDS ----
    for (int i = tid; i < 128 * 32; i += 256) {
        int r  = i >> 5;
        int c4 = (i & 31) * 4;
        float4 v = *(const float4*)(x + (rowbase + r) * 128 + c4);
        ushort4 pk;
        pk.x = f32_bf16(v.x); pk.y = f32_bf16(v.y);
        pk.z = f32_bf16(v.z); pk.w = f32_bf16(v.w);
        *(ushort4*)&xs[r * XS + c4] = pk;
    }
    __syncthreads();

    // ---- A fragments: 8 named SSA values (32 VGPRs), read from LDS once ----
    // A-operand layout: A[m = lane&15][k = quad*8 + j]; wave rows wave*32..+31
    const unsigned short* xb = &xs[(wave * 32 + l15) * XS + quad * 8];
    bf16x8 a00 = *(const bf16x8*)(xb +  0);
    bf16x8 a01 = *(const bf16x8*)(xb + 32);
    bf16x8 a02 = *(const bf16x8*)(xb + 64);
    bf16x8 a03 = *(const bf16x8*)(xb + 96);
    bf16x8 a10 = *(const bf16x8*)(xb + 16 * XS +  0);
    bf16x8 a11 = *(const bf16x8*)(xb + 16 * XS + 32);
    bf16x8 a12 = *(const bf16x8*)(xb + 16 * XS + 64);
    bf16x8 a13 = *(const bf16x8*)(xb + 16 * XS + 96);

    const int rb = wave * 32 + quad * 4;      // C/D: row = quad*4 + reg (+ mt*16)

    #pragma unroll 1
    for (int e = 0; e < 2; ++e) {
        const bf16x8* wb8  = (const bf16x8*)wbf + (long)e * 8192 + lane;
        const float*  b1p  = b1 + e * 512 + l15 * 32;
        const float*  w2ap = w2 + e * 1024 + l15 * 32;
        const float*  w2bp = w2ap + 512;

        // 16 named accumulators, reused across the two expert iterations
        float p000=0.f,p001=0.f,p010=0.f,p011=0.f,p020=0.f,p021=0.f,p030=0.f,p031=0.f;
        float p100=0.f,p101=0.f,p110=0.f,p111=0.f,p120=0.f,p121=0.f,p130=0.f,p131=0.f;

        #pragma unroll 1
        for (int nt = 0; nt < 32; ++nt) {
            const bf16x8* wp = wb8 + nt * 256;
            bf16x8 q0 = wp[0];
            bf16x8 q1 = wp[64];
            bf16x8 q2 = wp[128];
            bf16x8 q3 = wp[192];
            float bb = b1p[nt];
            float wa = w2ap[nt];
            float wc = w2bp[nt];
            float h;
            {   // m-tile 0
                floatx4 c = {bb, bb, bb, bb};
                c = __builtin_amdgcn_mfma_f32_16x16x32_bf16(a00, q0, c, 0, 0, 0);
                c = __builtin_amdgcn_mfma_f32_16x16x32_bf16(a01, q1, c, 0, 0, 0);
                c = __builtin_amdgcn_mfma_f32_16x16x32_bf16(a02, q2, c, 0, 0, 0);
                c = __builtin_amdgcn_mfma_f32_16x16x32_bf16(a03, q3, c, 0, 0, 0);
                h = fmaxf(c[0], 0.f); p000 = fmaf(h, wa, p000); p001 = fmaf(h, wc, p001);
                h = fmaxf(c[1], 0.f); p010 = fmaf(h, wa, p010); p011 = fmaf(h, wc, p011);
                h = fmaxf(c[2], 0.f); p020 = fmaf(h, wa, p020); p021 = fmaf(h, wc, p021);
                h = fmaxf(c[3], 0.f); p030 = fmaf(h, wa, p030); p031 = fmaf(h, wc, p031);
            }
            {   // m-tile 1
                floatx4 c = {bb, bb, bb, bb};
                c = __builtin_amdgcn_mfma_f32_16x16x32_bf16(a10, q0, c, 0, 0, 0);
                c = __builtin_amdgcn_mfma_f32_16x16x32_bf16(a11, q1, c, 0, 0, 0);
                c = __builtin_amdgcn_mfma_f32_16x16x32_bf16(a12, q2, c, 0, 0, 0);
                c = __builtin_amdgcn_mfma_f32_16x16x32_bf16(a13, q3, c, 0, 0, 0);
                h = fmaxf(c[0], 0.f); p100 = fmaf(h, wa, p100); p101 = fmaf(h, wc, p101);
                h = fmaxf(c[1], 0.f); p110 = fmaf(h, wa, p110); p111 = fmaf(h, wc, p111);
                h = fmaxf(c[2], 0.f); p120 = fmaf(h, wa, p120); p121 = fmaf(h, wc, p121);
                h = fmaxf(c[3], 0.f); p130 = fmaf(h, wa, p130); p131 = fmaf(h, wc, p131);
            }
        }

        // reduce across the 16 column-lanes, store this expert's rows
        red_store(p000, p001, rb +  0, e, out_s, l15);
        red_store(p010, p011, rb +  1, e, out_s, l15);
        red_store(p020, p021, rb +  2, e, out_s, l15);
        red_store(p030, p031, rb +  3, e, out_s, l15);
        red_store(p100, p101, rb + 16, e, out_s, l15);
        red_store(p110, p111, rb + 17, e, out_s, l15);
        red_store(p120, p121, rb + 18, e, out_s, l15);
        red_store(p130, p131, rb + 19, e, out_s, l15);
    }
    __syncthreads();

    // ---- select expert per row, add b2, coalesced store ----
    {
        int r  = tid >> 1;
        int o  = tid & 1;
        int te = t_s[r];
        out[(rowbase + r) * 2 + o] = out_s[r][te][o] + b2[te * 2 + o];
    }
}

extern "C" void kernel_launch(void* const* d_in, const int* in_sizes, int n_in,
                              void* d_out, int out_size, void* d_ws, size_t ws_size,
                              hipStream_t stream) {
    const float* x      = (const float*)d_in[0];
    const float* w1     = (const float*)d_in[1];
    const float* b1     = (const float*)d_in[2];
    const float* w2     = (const float*)d_in[3];
    const float* b2     = (const float*)d_in[4];
    const float* protos = (const float*)d_in[5];
    float* out = (float*)d_out;
    unsigned short* wbf = (unsigned short*)d_ws;   // 256 KiB bf16 fragment-ordered w1

    prep_w1_frag<<<dim3(64), dim3(256), 0, stream>>>(w1, wbf);
    moe_fused<<<dim3(1024), dim3(256), 0, stream>>>(x, wbf, b1, w2, b2, protos, out);
}

// Round 9
// 166.257 us; speedup vs baseline: 1.3467x; 1.3467x over previous
//
#include <hip/hip_runtime.h>

typedef __bf16 bf16x8 __attribute__((ext_vector_type(8)));
typedef float floatx4 __attribute__((ext_vector_type(4)));

#define XS 136  // LDS row stride in bf16 elements (272 B -> 2-way bank aliasing = free)

__device__ __forceinline__ unsigned short f32_bf16(float f) {
    union { float f; unsigned int u; } c; c.f = f;
    return (unsigned short)((c.u + 0x7fffu + ((c.u >> 16) & 1u)) >> 16);  // RNE, finite inputs
}

// w1 -> MFMA B-fragment order, hidden-col mapping h(nt,l15) = l15*32 + nt.
// frag f = (e*32+nt)*4+ks ; lane (quad,l15) holds B[k=quad*8+j][n=l15] = w1[e][h][k]
__global__ __launch_bounds__(256) void prep_w1_frag(const float* __restrict__ w1,
                                                    unsigned short* __restrict__ wbf) {
    int g    = blockIdx.x * 256 + threadIdx.x;   // 64 blocks -> 16384 threads
    int lane = g & 63;
    int frag = g >> 6;                            // 0..255
    int ks   = frag & 3;
    int nt   = (frag >> 2) & 31;
    int e    = frag >> 7;
    int l15  = lane & 15;
    int quad = lane >> 4;
    int h    = l15 * 32 + nt;
    const float* src = w1 + ((e * 512 + h) * 128 + ks * 32 + quad * 8);
    unsigned short* dst = wbf + (long)g * 8;      // 16 B/lane, contiguous per wave
    #pragma unroll
    for (int j = 0; j < 8; ++j) dst[j] = f32_bf16(src[j]);
}

__device__ __forceinline__ void red_store(float v0, float v1, int r, int e,
                                          float (*outs)[2][2], int l15) {
    v0 += __shfl_xor(v0, 1);  v1 += __shfl_xor(v1, 1);
    v0 += __shfl_xor(v0, 2);  v1 += __shfl_xor(v1, 2);
    v0 += __shfl_xor(v0, 4);  v1 += __shfl_xor(v1, 4);
    v0 += __shfl_xor(v0, 8);  v1 += __shfl_xor(v1, 8);
    if (l15 == 0) { outs[r][e][0] = v0; outs[r][e][1] = v1; }
}

// 512 blocks x 256 rows, 512 threads (8 waves). Wave w = (mh = w&3, e = w>>2):
// 64 rows x expert e. A = 16 NAMED bf16x8 (64 VGPRs), LDS-read ONCE — zero
// in-loop LDS. launch_bounds(512,2) -> 256-VGPR cap (the R7 spill was cap 128).
// Barrier every 2 nt phase-locks the 4 waves sharing each expert's weight
// stream into one 8 KiB L1 window -> misses paid once per block, not per wave.
__global__ __launch_bounds__(512, 2) void moe_fused(
    const float* __restrict__ x,
    const unsigned short* __restrict__ wbf,   // fragment-ordered bf16 w1
    const float* __restrict__ b1,             // [2][512]
    const float* __restrict__ w2,             // [2][2][512]
    const float* __restrict__ b2,             // [2][2]
    const float* __restrict__ protos,         // [2][128]
    float* __restrict__ out)                  // [B][2]
{
    __shared__ unsigned short xs[256 * XS];   // 69632 B
    __shared__ float out_s[256][2][2];        // 4096 B
    __shared__ int   t_s[256];                // 1024 B -> 74752 B total

    const int tid  = threadIdx.x;
    const int lane = tid & 63;
    const int wave = tid >> 6;
    const int quad = lane >> 4;
    const int l15  = lane & 15;
    const int mh   = wave & 3;
    const int e    = wave >> 2;
    const long rowbase = (long)blockIdx.x * 256;

    // ---- routing: t = (d1<d0) via sign of sum (p0-p1)*(0.5*(p0+p1)-x), fp64 ----
    {
        int r   = tid >> 1;                   // 2 threads per row, 256 rows
        int sub = tid & 1;
        const float* xr = x + (rowbase + r) * 128 + sub * 64;
        const float* p0 = protos + sub * 64;
        const float* p1 = protos + 128 + sub * 64;
        double acc = 0.0;
        #pragma unroll
        for (int k = 0; k < 16; ++k) {
            float4 xv = *(const float4*)(xr + k * 4);
            float4 a  = *(const float4*)(p0 + k * 4);
            float4 b  = *(const float4*)(p1 + k * 4);
            acc += ((double)a.x - b.x) * (0.5 * ((double)a.x + b.x) - xv.x);
            acc += ((double)a.y - b.y) * (0.5 * ((double)a.y + b.y) - xv.y);
            acc += ((double)a.z - b.z) * (0.5 * ((double)a.z + b.z) - xv.z);
            acc += ((double)a.w - b.w) * (0.5 * ((double)a.w + b.w) - xv.w);
        }
        acc += __shfl_xor(acc, 1);
        if (sub == 0) t_s[r] = (acc > 0.0) ? 1 : 0;   // tie -> expert 0 (numpy argmin)
    }

    // ---- stage x tile: coalesced float4 global reads -> bf16 LDS ----
    for (int i = tid; i < 256 * 32; i += 512) {
        int r  = i >> 5;
        int c4 = (i & 31) * 4;
        float4 v = *(const float4*)(x + (rowbase + r) * 128 + c4);
        ushort4 pk;
        pk.x = f32_bf16(v.x); pk.y = f32_bf16(v.y);
        pk.z = f32_bf16(v.z); pk.w = f32_bf16(v.w);
        *(ushort4*)&xs[r * XS + c4] = pk;
    }
    __syncthreads();

    // ---- A fragments: 16 named SSA values (64 VGPRs), read from LDS once ----
    // A-operand layout: A[m = lane&15][k = quad*8 + j]; wave rows mh*64..+63
    const unsigned short* xb = &xs[(mh * 64 + l15) * XS + quad * 8];
    bf16x8 a00 = *(const bf16x8*)(xb + 0 * 16 * XS +  0);
    bf16x8 a01 = *(const bf16x8*)(xb + 0 * 16 * XS + 32);
    bf16x8 a02 = *(const bf16x8*)(xb + 0 * 16 * XS + 64);
    bf16x8 a03 = *(const bf16x8*)(xb + 0 * 16 * XS + 96);
    bf16x8 a10 = *(const bf16x8*)(xb + 1 * 16 * XS +  0);
    bf16x8 a11 = *(const bf16x8*)(xb + 1 * 16 * XS + 32);
    bf16x8 a12 = *(const bf16x8*)(xb + 1 * 16 * XS + 64);
    bf16x8 a13 = *(const bf16x8*)(xb + 1 * 16 * XS + 96);
    bf16x8 a20 = *(const bf16x8*)(xb + 2 * 16 * XS +  0);
    bf16x8 a21 = *(const bf16x8*)(xb + 2 * 16 * XS + 32);
    bf16x8 a22 = *(const bf16x8*)(xb + 2 * 16 * XS + 64);
    bf16x8 a23 = *(const bf16x8*)(xb + 2 * 16 * XS + 96);
    bf16x8 a30 = *(const bf16x8*)(xb + 3 * 16 * XS +  0);
    bf16x8 a31 = *(const bf16x8*)(xb + 3 * 16 * XS + 32);
    bf16x8 a32 = *(const bf16x8*)(xb + 3 * 16 * XS + 64);
    bf16x8 a33 = *(const bf16x8*)(xb + 3 * 16 * XS + 96);

    // ---- 32 named accumulators: o<mt><rg><o> ----
    float o000=0.f,o001=0.f,o010=0.f,o011=0.f,o020=0.f,o021=0.f,o030=0.f,o031=0.f;
    float o100=0.f,o101=0.f,o110=0.f,o111=0.f,o120=0.f,o121=0.f,o130=0.f,o131=0.f;
    float o200=0.f,o201=0.f,o210=0.f,o211=0.f,o220=0.f,o221=0.f,o230=0.f,o231=0.f;
    float o300=0.f,o301=0.f,o310=0.f,o311=0.f,o320=0.f,o321=0.f,o330=0.f,o331=0.f;

    const bf16x8* wb8  = (const bf16x8*)wbf + (long)e * 8192 + lane;  // e*32*4*64
    const float*  b1p  = b1 + e * 512 + l15 * 32;
    const float*  w2ap = w2 + e * 1024 + l15 * 32;
    const float*  w2bp = w2ap + 512;

#define MT_BODY(A0,A1,A2,A3, O00,O01,O10,O11,O20,O21,O30,O31) do {               \
        floatx4 c = {bb, bb, bb, bb};                                            \
        c = __builtin_amdgcn_mfma_f32_16x16x32_bf16(A0, q0, c, 0, 0, 0);         \
        c = __builtin_amdgcn_mfma_f32_16x16x32_bf16(A1, q1, c, 0, 0, 0);         \
        c = __builtin_amdgcn_mfma_f32_16x16x32_bf16(A2, q2, c, 0, 0, 0);         \
        c = __builtin_amdgcn_mfma_f32_16x16x32_bf16(A3, q3, c, 0, 0, 0);         \
        float h;                                                                 \
        h = fmaxf(c[0], 0.f); O00 = fmaf(h, wa, O00); O01 = fmaf(h, wc, O01);    \
        h = fmaxf(c[1], 0.f); O10 = fmaf(h, wa, O10); O11 = fmaf(h, wc, O11);    \
        h = fmaxf(c[2], 0.f); O20 = fmaf(h, wa, O20); O21 = fmaf(h, wc, O21);    \
        h = fmaxf(c[3], 0.f); O30 = fmaf(h, wa, O30); O31 = fmaf(h, wc, O31);    \
    } while (0)

    #pragma unroll 1
    for (int ntc = 0; ntc < 32; ntc += 2) {
        __syncthreads();   // phase-lock: all waves in the same 2-nt L1 window
        #pragma unroll
        for (int u = 0; u < 2; ++u) {
            const int nt = ntc + u;
            const bf16x8* wp = wb8 + nt * 256;
            bf16x8 q0 = wp[0];
            bf16x8 q1 = wp[64];
            bf16x8 q2 = wp[128];
            bf16x8 q3 = wp[192];
            float bb = b1p[nt];
            float wa = w2ap[nt];
            float wc = w2bp[nt];
            MT_BODY(a00,a01,a02,a03, o000,o001,o010,o011,o020,o021,o030,o031);
            MT_BODY(a10,a11,a12,a13, o100,o101,o110,o111,o120,o121,o130,o131);
            MT_BODY(a20,a21,a22,a23, o200,o201,o210,o211,o220,o221,o230,o231);
            MT_BODY(a30,a31,a32,a33, o300,o301,o310,o311,o320,o321,o330,o331);
        }
    }
#undef MT_BODY

    // ---- reduce layer-2 partials across the 16 column-lanes, store ----
    const int rb = mh * 64 + quad * 4;   // C/D: row = quad*4 + reg (+ mt*16)
    red_store(o000, o001, rb +  0, e, out_s, l15);
    red_store(o010, o011, rb +  1, e, out_s, l15);
    red_store(o020, o021, rb +  2, e, out_s, l15);
    red_store(o030, o031, rb +  3, e, out_s, l15);
    red_store(o100, o101, rb + 16, e, out_s, l15);
    red_store(o110, o111, rb + 17, e, out_s, l15);
    red_store(o120, o121, rb + 18, e, out_s, l15);
    red_store(o130, o131, rb + 19, e, out_s, l15);
    red_store(o200, o201, rb + 32, e, out_s, l15);
    red_store(o210, o211, rb + 33, e, out_s, l15);
    red_store(o220, o221, rb + 34, e, out_s, l15);
    red_store(o230, o231, rb + 35, e, out_s, l15);
    red_store(o300, o301, rb + 48, e, out_s, l15);
    red_store(o310, o311, rb + 49, e, out_s, l15);
    red_store(o320, o321, rb + 50, e, out_s, l15);
    red_store(o330, o331, rb + 51, e, out_s, l15);
    __syncthreads();

    // ---- select expert per row, add b2, coalesced store ----
    {
        int r  = tid >> 1;
        int o  = tid & 1;
        int te = t_s[r];
        out[(rowbase + r) * 2 + o] = out_s[r][te][o] + b2[te * 2 + o];
    }
}

extern "C" void kernel_launch(void* const* d_in, const int* in_sizes, int n_in,
                              void* d_out, int out_size, void* d_ws, size_t ws_size,
                              hipStream_t stream) {
    const float* x      = (const float*)d_in[0];
    const float* w1     = (const float*)d_in[1];
    const float* b1     = (const float*)d_in[2];
    const float* w2     = (const float*)d_in[3];
    const float* b2     = (const float*)d_in[4];
    const float* protos = (const float*)d_in[5];
    float* out = (float*)d_out;
    unsigned short* wbf = (unsigned short*)d_ws;   // 256 KiB bf16 fragment-ordered w1

    prep_w1_frag<<<dim3(64), dim3(256), 0, stream>>>(w1, wbf);
    moe_fused<<<dim3(512), dim3(512), 0, stream>>>(x, wbf, b1, w2, b2, protos, out);
}